// Round 7
// baseline (218.121 us; speedup 1.0000x reference)
//
#include <hip/hip_runtime.h>

using u16 = unsigned short;
using u32 = unsigned int;

typedef __bf16 bf16x8 __attribute__((ext_vector_type(8)));
typedef float  f32x4  __attribute__((ext_vector_type(4)));

__device__ __forceinline__ u16 f2bf(float f) {
    u32 u = __float_as_uint(f);
    u32 r = u + 0x7fffu + ((u >> 16) & 1u);
    return (u16)(r >> 16);
}
__device__ __forceinline__ float gelu_f(float x) {
    return 0.5f * x * (1.0f + erff(x * 0.70710678118654752440f));
}

#define GLOAD16(gp, lp) __builtin_amdgcn_global_load_lds( \
    (const __attribute__((address_space(1))) void*)(gp),  \
    (__attribute__((address_space(3))) void*)(lp), 16, 0, 0)
#define WAITV(n) asm volatile("s_waitcnt vmcnt(" #n ")" ::: "memory")
#define WAITL0   asm volatile("s_waitcnt lgkmcnt(0)" ::: "memory")

// ---------------- prep: cvt W1/W2 to bf16 with bank-swizzle baked in ----------------
// W'[f][ (k&~31) | ((((k>>3)&3) ^ (f&3))<<3) | (k&7) ] = W[f][k]
__global__ __launch_bounds__(256) void prep_kernel(
    const float* __restrict__ W1, const float* __restrict__ W2,
    u16* __restrict__ W1b, u16* __restrict__ W2b)
{
    int i = blockIdx.x * 256 + threadIdx.x;          // 0..131071
    const float* src = (i < 65536) ? W1 : W2;
    u16* dst = (i < 65536) ? W1b : W2b;
    int ii = i & 65535;
    int f = ii >> 7;
    int k = (ii & 127) * 4;
    float4 v = ((const float4*)src)[ii];
    int kd = (k & ~31) | ((((k >> 3) & 3) ^ (f & 3)) << 3) | (k & 7);
    ushort4 o;
    o.x = f2bf(v.x); o.y = f2bf(v.y); o.z = f2bf(v.z); o.w = f2bf(v.w);
    *(ushort4*)&dst[f * 512 + kd] = o;
}

// ---------------- mega: full 2-layer GAT per graph, 1 block/graph, 8 waves ----------------
// LDS: Hs 128KB (x-bf16 -> H1^T -> H1' -> H2^T), SG 32KB:
//   [0,8K) cnt u4[128][128] packed in u32[128][16]
//   [8K,24K) per-wave W ring: wave w at +w*2KB, 2 buffers x 1KB (16 f-rows x 32 k)
//   [24K,26K) stats f32[512]: ss[128] sd[128] M[128] rD[128]
__global__ __launch_bounds__(512, 2) void mega_kernel(
    const float* __restrict__ x, const int* __restrict__ ei, const int* __restrict__ valid,
    const u16* __restrict__ W1b, const float* __restrict__ a1s, const float* __restrict__ a1d,
    const float* __restrict__ b1,
    const u16* __restrict__ W2b, const float* __restrict__ a2s, const float* __restrict__ a2d,
    const float* __restrict__ b2,
    float* __restrict__ outF)
{
    __shared__ u16 Hs[65536];
    __shared__ __align__(16) u16 SG[16384];
    u32*   cntw = (u32*)SG;                 // [0, 8K) bytes
    u16*   ring = SG + 4096;                // [8K, 24K) bytes (elem offset 4096)
    float* stf  = (float*)(SG + 12288);     // [24K, 26K) bytes

    const int tid  = threadIdx.x;
    const int lane = tid & 63;
    const int w    = tid >> 6;
    const int rl   = lane & 15;
    const int grp  = lane >> 4;
    const int gid  = blockIdx.x;
    const int bb   = gid >> 5, tt = gid & 31;

    // ---- phase 0: edge prefetch, cnt/stats zero, x -> bf16 Hs ----
    const int4* es = (const int4*)(ei + (size_t)gid * 4096);
    int4 e0 = es[tid], e1 = es[512 + tid];

    for (int i = tid; i < 2048; i += 512) cntw[i] = 0u;
    stf[tid] = 0.f;

    const float4* xg = (const float4*)(x + (size_t)gid * 65536);
    #pragma unroll
    for (int it = 0; it < 16; ++it) {
        float4 a = xg[tid * 2 + it * 1024];
        float4 b = xg[tid * 2 + 1 + it * 1024];
        int m = it * 8 + w;
        int sp = lane ^ ((lane >> 3) & 7) ^ (m & 7);
        ushort4 lo, hi;
        lo.x = f2bf(a.x); lo.y = f2bf(a.y); lo.z = f2bf(a.z); lo.w = f2bf(a.w);
        hi.x = f2bf(b.x); hi.y = f2bf(b.y); hi.z = f2bf(b.z); hi.w = f2bf(b.w);
        *(ushort4*)&Hs[m * 512 + sp * 8]     = lo;
        *(ushort4*)&Hs[m * 512 + sp * 8 + 4] = hi;
    }
    __syncthreads();

    // ---- edge-count scatter (u4 nibbles), once for both layers ----
    atomicAdd(&cntw[e1.x * 16 + (e0.x >> 3)], 1u << ((e0.x & 7) * 4));
    atomicAdd(&cntw[e1.y * 16 + (e0.y >> 3)], 1u << ((e0.y & 7) * 4));
    atomicAdd(&cntw[e1.z * 16 + (e0.z >> 3)], 1u << ((e0.z & 7) * 4));
    atomicAdd(&cntw[e1.w * 16 + (e0.w >> 3)], 1u << ((e0.w & 7) * 4));
    if (tid < 128) atomicAdd(&cntw[tid * 16 + (tid >> 3)], 1u << ((tid & 7) * 4));
    __syncthreads();

    u16* myring = ring + w * 1024;

    for (int L = 0; L < 2; ++L) {
        const u16*  WL  = L ? W2b : W1b;
        const float* av_s = L ? a2s : a1s;
        const float* av_d = L ? a2d : a1d;

        // ---- GEMM: acc[i][j] = C[m=i*16.., f=w*64+j*16..]; barrier-free k-loop ----
        f32x4 acc[8][4] = {};
        {
            auto STAGEW = [&](int q) {
                int kt2 = q >> 2, j2 = q & 3;
                const u16* src = WL + (size_t)(w * 64 + j2 * 16 + (lane >> 2)) * 512
                               + kt2 * 32 + (lane & 3) * 8;
                GLOAD16(src, &myring[(q & 1) * 512]);
            };
            STAGEW(0); STAGEW(1);
            for (int kt = 0; kt < 16; ++kt) {
                bf16x8 af[8];
                #pragma unroll
                for (int i = 0; i < 8; ++i) {
                    int m = i * 16 + rl;
                    int sp = (kt * 4 + grp) ^ (kt >> 1) ^ (m & 7);
                    af[i] = *(const bf16x8*)&Hs[m * 512 + sp * 8];
                }
                #pragma unroll
                for (int j = 0; j < 4; ++j) {
                    int q = kt * 4 + j;
                    if (kt == 15 && j == 3) { WAITV(0); } else { WAITV(1); }
                    bf16x8 bv = *(const bf16x8*)&myring[(q & 1) * 512 + rl * 32 + ((grp ^ (rl & 3)) * 8)];
                    WAITL0;
                    __builtin_amdgcn_sched_barrier(0);
                    if (q + 2 < 64) STAGEW(q + 2);
                    #pragma unroll
                    for (int i = 0; i < 8; ++i)
                        acc[i][j] = __builtin_amdgcn_mfma_f32_16x16x32_bf16(af[i], bv, acc[i][j], 0, 0, 0);
                }
            }
        }
        __syncthreads();   // all Hs(A) reads done -> safe to overwrite with H^T

        // ---- epilogue: H^T -> Hs (swizzled) + fused scores into stf ----
        {
            float asv[4], adv[4];
            #pragma unroll
            for (int j = 0; j < 4; ++j) {
                int f = w * 64 + j * 16 + rl;
                asv[j] = av_s[f]; adv[j] = av_d[f];
            }
            #pragma unroll
            for (int i = 0; i < 8; ++i) {
                #pragma unroll
                for (int j = 0; j < 4; ++j) {
                    int f = j * 16 + rl + w * 64;
                    int oct = i * 2 + (grp >> 1);
                    int elem = f * 128 + ((oct ^ (f & 15)) * 8) + (grp & 1) * 4;
                    ushort4 o;
                    o.x = f2bf(acc[i][j][0]); o.y = f2bf(acc[i][j][1]);
                    o.z = f2bf(acc[i][j][2]); o.w = f2bf(acc[i][j][3]);
                    *(ushort4*)&Hs[elem] = o;
                }
                #pragma unroll
                for (int r = 0; r < 4; ++r) {
                    float s = acc[i][0][r] * asv[0] + acc[i][1][r] * asv[1]
                            + acc[i][2][r] * asv[2] + acc[i][3][r] * asv[3];
                    float d = acc[i][0][r] * adv[0] + acc[i][1][r] * adv[1]
                            + acc[i][2][r] * adv[2] + acc[i][3][r] * adv[3];
                    #pragma unroll
                    for (int off = 1; off < 16; off <<= 1) {
                        s += __shfl_xor(s, off);
                        d += __shfl_xor(d, off);
                    }
                    if (rl == 0) {
                        int m = i * 16 + grp * 4 + r;
                        atomicAdd(&stf[m], s);
                        atomicAdd(&stf[128 + m], d);
                    }
                }
            }
        }
        __syncthreads();

        // ---- softmax stats M, 1/D per dst row ----
        for (int r = 0; r < 16; ++r) {
            int m = w * 16 + r;
            float sdm = stf[128 + m];
            u32 w0 = cntw[m * 16 + (lane >> 3)];
            u32 w1 = cntw[m * 16 + 8 + (lane >> 3)];
            u32 c0 = (w0 >> ((lane & 7) * 4)) & 15u;
            u32 c1 = (w1 >> ((lane & 7) * 4)) & 15u;
            float E0 = stf[lane] + sdm;      E0 = E0 > 0.f ? E0 : 0.2f * E0;
            float E1 = stf[lane + 64] + sdm; E1 = E1 > 0.f ? E1 : 0.2f * E1;
            float mx = fmaxf(c0 ? E0 : -1e30f, c1 ? E1 : -1e30f);
            #pragma unroll
            for (int off = 1; off < 64; off <<= 1) mx = fmaxf(mx, __shfl_xor(mx, off));
            float p = (c0 ? (float)c0 * __expf(E0 - mx) : 0.f)
                    + (c1 ? (float)c1 * __expf(E1 - mx) : 0.f);
            #pragma unroll
            for (int off = 1; off < 64; off <<= 1) p += __shfl_xor(p, off);
            if (lane == 0) { stf[256 + m] = mx; stf[384 + m] = 1.f / p; }
        }
        __syncthreads();

        // ---- AGG: C[m][f] = sum_s P[m][s] H[s][f] ----
        f32x4 acc2[32] = {};
        {
            int m = w * 16 + rl;
            float sdm = stf[128 + m], Mm = stf[256 + m], rDm = stf[384 + m];
            bf16x8 pa[4];
            #pragma unroll
            for (int kb = 0; kb < 4; ++kb) {
                u32 word = cntw[m * 16 + kb * 4 + grp];
                #pragma unroll
                for (int e = 0; e < 8; ++e) {
                    u32 c = (word >> (e * 4)) & 15u;
                    int s = kb * 32 + grp * 8 + e;
                    float ev = stf[s] + sdm; ev = ev > 0.f ? ev : 0.2f * ev;
                    float p = c ? (float)c * __expf(ev - Mm) * rDm : 0.f;
                    pa[kb][e] = (__bf16)p;
                }
            }
            #pragma unroll
            for (int j = 0; j < 32; ++j) {
                int f = j * 16 + rl;
                #pragma unroll
                for (int kb = 0; kb < 4; ++kb) {
                    bf16x8 hb = *(const bf16x8*)&Hs[f * 128 + (((kb * 4 + grp) ^ rl) * 8)];
                    acc2[j] = __builtin_amdgcn_mfma_f32_16x16x32_bf16(pa[kb], hb, acc2[j], 0, 0, 0);
                }
            }
        }
        __syncthreads();   // H^T reads + stf/cnt reads done

        if (L == 0) {
            stf[tid] = 0.f;   // re-zero stats for layer 2 scores
            #pragma unroll
            for (int j = 0; j < 32; ++j) {
                int f = j * 16 + rl;
                float bv = b1[f];
                int slot = f >> 3;
                #pragma unroll
                for (int r = 0; r < 4; ++r) {
                    int m2 = w * 16 + grp * 4 + r;
                    int loc = slot ^ ((slot >> 3) & 7) ^ (m2 & 7);
                    Hs[m2 * 512 + loc * 8 + (f & 7)] = f2bf(gelu_f(acc2[j][r] + bv));
                }
            }
            __syncthreads();
        } else {
            float msk = (tt < valid[bb]) ? 1.f : 0.f;
            float* og = outF + (size_t)gid * 65536;
            #pragma unroll
            for (int j = 0; j < 32; ++j) {
                int f = j * 16 + rl;
                float bv = b2[f];
                #pragma unroll
                for (int r = 0; r < 4; ++r) {
                    int m2 = w * 16 + grp * 4 + r;
                    og[m2 * 512 + f] = (acc2[j][r] + bv) * msk;
                }
            }
        }
    }
}

// ---------------- time mix: out = gelu(W_time @ y + b_time) + y, in-place ----------------
__global__ __launch_bounds__(256) void timemix_kernel(float* __restrict__ y,
                                                      const float* __restrict__ Wt,
                                                      const float* __restrict__ bt) {
    __shared__ float wsm[1024];
    __shared__ float bts[32];
    int tid = threadIdx.x;
    for (int i = tid; i < 1024; i += 256) wsm[i] = Wt[i];
    if (tid < 32) bts[tid] = bt[tid];
    __syncthreads();
    int blk = blockIdx.x;               // 2048 blocks
    int b = blk >> 8;
    int rem = blk & 255;
    int n = rem >> 1;
    int f = (rem & 1) * 256 + tid;
    size_t base = ((size_t)b * 4096 + n) * 512 + f;
    float ys[32];
    #pragma unroll
    for (int s = 0; s < 32; ++s) ys[s] = y[base + (size_t)s * 65536];
    #pragma unroll
    for (int t = 0; t < 32; ++t) {
        float a = bts[t];
        #pragma unroll
        for (int s = 0; s < 32; ++s) a += wsm[t * 32 + s] * ys[s];
        y[base + (size_t)t * 65536] = gelu_f(a) + ys[t];
    }
}

extern "C" void kernel_launch(void* const* d_in, const int* in_sizes, int n_in,
                              void* d_out, int out_size, void* d_ws, size_t ws_size,
                              hipStream_t stream) {
    const float* x     = (const float*)d_in[0];
    const int*   ei    = (const int*)d_in[1];
    const int*   valid = (const int*)d_in[2];
    const float* W1    = (const float*)d_in[3];
    const float* a1s   = (const float*)d_in[4];
    const float* a1d   = (const float*)d_in[5];
    const float* b1    = (const float*)d_in[6];
    const float* W2    = (const float*)d_in[7];
    const float* a2s   = (const float*)d_in[8];
    const float* a2d   = (const float*)d_in[9];
    const float* b2    = (const float*)d_in[10];
    const float* Wt    = (const float*)d_in[11];
    const float* bt    = (const float*)d_in[12];
    float* out = (float*)d_out;

    char* ws = (char*)d_ws;
    u16* W1b = (u16*)(ws);            // 524,288 B (bf16, bank-swizzled)
    u16* W2b = (u16*)(ws + 524288);   // 524,288 B

    prep_kernel<<<512, 256, 0, stream>>>(W1, W2, W1b, W2b);
    mega_kernel<<<256, 512, 0, stream>>>(x, ei, valid,
        W1b, a1s, a1d, b1, W2b, a2s, a2d, b2, out);
    timemix_kernel<<<2048, 256, 0, stream>>>(out, Wt, bt);
}